// Round 20
// baseline (1208.224 us; speedup 1.0000x reference)
//
#include <hip/hip_runtime.h>

typedef _Float16 half8 __attribute__((ext_vector_type(8)));
typedef float floatx4 __attribute__((ext_vector_type(4)));

#define DEV_INLINE __device__ __forceinline__

constexpr int D0 = 512, D1 = 256, D2 = 256, D3 = 128;
constexpr int NROWS = 16384;
constexpr int MBLK = 32;            // batch rows per block (spill-free tile)
constexpr int NBLK = NROWS / MBLK;  // 512 blocks (r16-proven geometry)
constexpr int KITERS = 16;
constexpr float ETA = 0.1f;

// packed-weight element offsets (fp16 elements) inside d_ws
constexpr int OFF_WF0 = 0;                  // fwd W0: K=256, N=512
constexpr int OFF_WF1 = OFF_WF0 + D1 * D0;  // fwd W1: K=256, N=256
constexpr int OFF_WF2 = OFF_WF1 + D2 * D1;  // fwd W2: K=128, N=256
constexpr int OFF_WB0 = OFF_WF2 + D3 * D2;  // bwd W0^T: K=512, N=256
constexpr int OFF_WB1 = OFF_WB0 + D0 * D1;  // bwd W1^T: K=256, N=256
constexpr int OFF_WB2 = OFF_WB1 + D1 * D2;  // bwd W2^T: K=256, N=128
constexpr int PACK_ELEMS = OFF_WB2 + D2 * D3;  // 458752 elems = 896 KB fp16

// ---------------------------------------------------------------------------
// Repack weights into MFMA B-fragment order.
// B-frag layout (16x16x32): lane l supplies B[kt*32 + (l>>4)*8 + j][nt*16 + (l&15)],
// j=0..7 contiguous -> pack index ((kt*NT + nt)*64 + l)*8 + j.
// ---------------------------------------------------------------------------
__global__ void repack_kernel(const float* __restrict__ W0, const float* __restrict__ W1,
                              const float* __restrict__ W2, _Float16* __restrict__ pack) {
  int p = blockIdx.x * 256 + threadIdx.x;
  if (p >= PACK_ELEMS) return;
  const float* W; int Csrc, Nd, off; bool tr;
  if (p < OFF_WF1)      { W = W0; Csrc = D0; Nd = D0; off = OFF_WF0; tr = false; }
  else if (p < OFF_WF2) { W = W1; Csrc = D1; Nd = D1; off = OFF_WF1; tr = false; }
  else if (p < OFF_WB0) { W = W2; Csrc = D2; Nd = D2; off = OFF_WF2; tr = false; }
  else if (p < OFF_WB1) { W = W0; Csrc = D0; Nd = D1; off = OFF_WB0; tr = true;  }
  else if (p < OFF_WB2) { W = W1; Csrc = D1; Nd = D1; off = OFF_WB1; tr = true;  }
  else                  { W = W2; Csrc = D2; Nd = D3; off = OFF_WB2; tr = true;  }
  int local = p - off;
  int j  = local & 7;
  int l  = (local >> 3) & 63;
  int fr = local >> 9;
  int NT = Nd >> 4;
  int nt = fr % NT, kt = fr / NT;
  int k = kt * 32 + ((l >> 4) << 3) + j;
  int n = nt * 16 + (l & 15);
  float v = tr ? W[n * Csrc + k] : W[k * Csrc + n];
  pack[p] = (_Float16)v;
}

DEV_INLINE float fast_tanh(float x) {
  float e = __expf(2.f * x);                       // v_exp_f32
  return 1.f - 2.f * __builtin_amdgcn_rcpf(e + 1.f);
}

DEV_INLINE const _Float16* bpt(const _Float16* Bp, int nt, int lane) {
  return Bp + ((size_t)nt * 64 + lane) * 8;
}

// ---------------------------------------------------------------------------
// Register-burst matmul: acc[rt*AS+ct] += A(RT*16 x KSTEPS*32) @ B[nt..nt+CT).
// ALL KSTEPS*CT B-tiles (<=8 = 32 VGPR) issued as one burst of ordinary
// global_load_dwordx4; compiler's per-register vmcnt waits pipeline ~8-deep
// (measured 2.45 TB/s in r14). A in LDS, fp16, row stride STRB bytes,
// XOR-swizzled by ((row&7)<<4). (The XOR only flips byte-offset bits 4..6,
// so a base pointer offset that is a multiple of 256 commutes with it.)
// ---------------------------------------------------------------------------
template <int RT, int KSTEPS, int CT, int NTT, int STRB, int AS>
DEV_INLINE void mm_burst(const char* __restrict__ A, const _Float16* __restrict__ bsrc,
                         int lane, floatx4* acc) {
  static_assert(KSTEPS * CT <= 8, "bq register budget");
  const int arow = lane & 15;
  const int aoff = (lane >> 4) << 4;  // byte offset of this lane's 16B k-chunk
  half8 bq[KSTEPS * CT];
#pragma unroll
  for (int s = 0; s < KSTEPS; ++s)
#pragma unroll
    for (int ct = 0; ct < CT; ++ct)
      bq[s * CT + ct] = *(const half8*)(bsrc + (size_t)(s * NTT + ct) * 512);
#pragma unroll
  for (int k0 = 0; k0 < KSTEPS; ++k0) {
    half8 a[RT];
#pragma unroll
    for (int rt = 0; rt < RT; ++rt) {
      int row = rt * 16 + arow;
      int byte = (row * STRB + k0 * 64 + aoff) ^ ((row & 7) << 4);
      a[rt] = *(const half8*)(A + byte);
    }
#pragma unroll
    for (int ct = 0; ct < CT; ++ct)
#pragma unroll
      for (int rt = 0; rt < RT; ++rt)
        acc[rt * AS + ct] =
            __builtin_amdgcn_mfma_f32_16x16x32_f16(a[rt], bq[k0 * CT + ct], acc[rt * AS + ct], 0, 0, 0);
  }
}

// ---------------------------------------------------------------------------
// Persistent settling kernel, MBLK=32 rows, 512 threads (8 waves), 96 KB LDS.
// r16 (991us, proven best) + x0-IN-LDS: since 2-block co-residence is proven
// unobtainable (r16/r17), the spare LDS is free -- the block's whole x0 slice
// (32x512 fp16 = 32 KB, XOR-swizzled) is parked in AX0 once at kernel start.
// This deletes the 32 scalar 2-byte global x0h loads per thread per iteration
// (the last global traffic besides weights) and lets iteration 0 read x0 as
// the P4 A-operand DIRECTLY from AX0 (STRB=1024), removing all iter-0 staging.
// LDS (96 KB): AX1[16K]@0: x1[32][256] s512 | AG0[8K]@16K: g0-quarter s256
//   AQ[16K]@24K: x2 s512 | AG1[16K]@40K: g1 s512 then g2 | AR[8K]@56K: x3 s256
//   AX0[32K]@64K: x0 [32][512] s1024 (read-only after init)
// Per iter: P1(+ep g1->AG1), {P3q(ep->AG0), B, P4q, B} x4, P4ep->AX1,
//           P2(ep: dx2a=-e2, g2->regs), P5, P5ep->AQ, B7, g2->AG1, B8,
//           P6, B9, P6ep->AR. 11 barriers/iter (draining __syncthreads,
//           r16-proven; r19's non-draining experiment regressed).
// Every C-cell is owned by exactly one thread -> fp16 RMW in LDS race-free.
// ---------------------------------------------------------------------------
__global__ __launch_bounds__(512)
void settle_kernel(const float* __restrict__ x0,
                   const _Float16* __restrict__ pack,
                   float* __restrict__ out) {
  extern __shared__ char lds[];
  char* AX1 = lds;
  char* AG0 = lds + 16384;
  char* AQ  = lds + 24576;
  char* AG1 = lds + 40960;
  char* AR  = lds + 57344;
  char* AX0 = lds + 65536;

  const int tid  = threadIdx.x;
  const int lane = tid & 63;
  const int wave = tid >> 6;
  const int row0 = blockIdx.x * MBLK;
  const int rsub = (lane >> 4) << 2;  // C/D layout: row = (lane>>4)*4 + i
  const int csub = lane & 15;         //             col = lane & 15

  // ---- park x0 slice in AX0 (fp16, XOR-swizzled), zero AQ/AR images
  {
    for (int idx = tid; idx < MBLK * D0; idx += 512) {
      int row = idx >> 9, col = idx & 511;
      _Float16 v = (_Float16)x0[(size_t)(row0 + row) * D0 + col];
      int byte = (row * 1024 + col * 2) ^ ((row & 7) << 4);
      *(_Float16*)(AX0 + byte) = v;
    }
    floatx4 z = {0.f, 0.f, 0.f, 0.f};
    for (int i = tid; i < 1024; i += 512) ((floatx4*)AQ)[i] = z;
    for (int i = tid; i < 512; i += 512) ((floatx4*)AR)[i] = z;
  }
  __syncthreads();  // AX0 + zeroed state images published

  const floatx4 zf = {0.f, 0.f, 0.f, 0.f};
  floatx4 x3m[2];  // fp32 master of the output layer [rt]
#pragma unroll
  for (int i = 0; i < 2; ++i) x3m[i] = zf;

  const _Float16* Wf0 = pack + OFF_WF0;
  const _Float16* Wf1 = pack + OFF_WF1;
  const _Float16* Wf2 = pack + OFF_WF2;
  const _Float16* Wb0 = pack + OFF_WB0;
  const _Float16* Wb1 = pack + OFF_WB1;
  const _Float16* Wb2 = pack + OFF_WB2;

  // =================== iteration 0 shortcut ===================
  // all states zero: g0 = x0 (f'(0)=1); only dx1 = x0 @ W0^T is nonzero.
  // P4 reads x0 DIRECTLY from AX0 (STRB=1024, k-offset q*256 B commutes with
  // the swizzle XOR). No staging, no barriers inside the q-loop.
  {
    floatx4 dx1a[4];
#pragma unroll
    for (int i = 0; i < 4; ++i) dx1a[i] = zf;
#pragma unroll
    for (int q = 0; q < 4; ++q)
      mm_burst<2, 4, 2, 16, 1024, 2>(AX0 + q * 256, bpt(Wb0 + q * 32768, wave * 2, lane),
                                     lane, dx1a);
#pragma unroll
    for (int rt = 0; rt < 2; ++rt)
#pragma unroll
      for (int ct = 0; ct < 2; ++ct) {
        int col = (wave * 2 + ct) * 16 + csub;
#pragma unroll
        for (int i = 0; i < 4; ++i) {
          int row = rt * 16 + rsub + i;
          float dx = fminf(1.f, fmaxf(-1.f, dx1a[rt * 2 + ct][i]));
          int byte = (row * 512 + col * 2) ^ ((row & 7) << 4);
          *(_Float16*)(AX1 + byte) = (_Float16)(ETA * dx);
        }
      }
    __syncthreads();  // publish x1
  }

  // =================== iterations 1..15 ===================
  for (int it = 1; it < KITERS; ++it) {
    floatx4 dx1a[4];
    // ---- P1: preact1 = x2 @ W1 (reads AQ); ep: e1, g1 -> AG1, dx1a = -e1
    {
#pragma unroll
      for (int i = 0; i < 4; ++i) dx1a[i] = zf;
#pragma unroll
      for (int ct = 0; ct < 2; ++ct)
        mm_burst<2, 8, 1, 16, 512, 2>(AQ, bpt(Wf1, wave * 2 + ct, lane), lane, &dx1a[ct]);
#pragma unroll
      for (int rt = 0; rt < 2; ++rt)
#pragma unroll
        for (int ct = 0; ct < 2; ++ct) {
          int col = (wave * 2 + ct) * 16 + csub;
#pragma unroll
          for (int i = 0; i < 4; ++i) {
            int row = rt * 16 + rsub + i;
            int sb = (row * 512 + col * 2) ^ ((row & 7) << 4);
            float t = fast_tanh(dx1a[rt * 2 + ct][i]);
            float x1o = (float)*(const _Float16*)(AX1 + sb);
            float e = x1o - t;
            *(_Float16*)(AG1 + sb) = (_Float16)(e * (1.f - t * t));
            dx1a[rt * 2 + ct][i] = -e;
          }
        }
    }
    // ---- P3/P4 interleaved over the four K/N=128 quarters of g0
    for (int q = 0; q < 4; ++q) {
      // P3q: preact0 cols q*128.. (each wave ONE tile nt = q*8+wave)
      {
        floatx4 acc3[2];
#pragma unroll
        for (int i = 0; i < 2; ++i) acc3[i] = zf;
        mm_burst<2, 8, 1, 32, 512, 1>(AX1, bpt(Wf0, q * 8 + wave, lane), lane, acc3);
        int colq = wave * 16 + csub;
#pragma unroll
        for (int rt = 0; rt < 2; ++rt)
#pragma unroll
          for (int i = 0; i < 4; ++i) {
            int row = rt * 16 + rsub + i;
            float t = fast_tanh(acc3[rt][i]);
            // x0 from LDS (AX0, swizzled) -- was 8 scalar global loads
            int xb = (row * 1024 + (q * 128 + colq) * 2) ^ ((row & 7) << 4);
            float xv = (float)*(const _Float16*)(AX0 + xb);
            float g = (xv - t) * (1.f - t * t);
            int byte = (row * 256 + colq * 2) ^ ((row & 7) << 4);
            *(_Float16*)(AG0 + byte) = (_Float16)g;
          }
      }
      __syncthreads();  // publish g0 quarter
      mm_burst<2, 4, 2, 16, 256, 2>(AG0, bpt(Wb0 + q * 32768, wave * 2, lane), lane, dx1a);
      __syncthreads();  // P4q reads done -> AG0 reusable
    }
    // ---- P4 epilogue: x1 += eta*clip(dx1a)  (RMW own cells of AX1)
#pragma unroll
    for (int rt = 0; rt < 2; ++rt)
#pragma unroll
      for (int ct = 0; ct < 2; ++ct) {
        int col = (wave * 2 + ct) * 16 + csub;
#pragma unroll
        for (int i = 0; i < 4; ++i) {
          int row = rt * 16 + rsub + i;
          int sb = (row * 512 + col * 2) ^ ((row & 7) << 4);
          float dx = fminf(1.f, fmaxf(-1.f, dx1a[rt * 2 + ct][i]));
          float x1o = (float)*(const _Float16*)(AX1 + sb);
          *(_Float16*)(AX1 + sb) = (_Float16)(x1o + ETA * dx);
        }
      }
    // ---- P2: preact2 = x3 @ W2 (reads AR); ep: dx2a = -e2, g2 -> registers
    floatx4 dx2a[4];
    half8 g2h[2];
    {
      floatx4 p2[4];
#pragma unroll
      for (int i = 0; i < 4; ++i) p2[i] = zf;
      mm_burst<2, 4, 2, 16, 256, 2>(AR, bpt(Wf2, wave * 2, lane), lane, p2);
#pragma unroll
      for (int rt = 0; rt < 2; ++rt)
#pragma unroll
        for (int ct = 0; ct < 2; ++ct) {
          int col = (wave * 2 + ct) * 16 + csub;
#pragma unroll
          for (int i = 0; i < 4; ++i) {
            int row = rt * 16 + rsub + i;
            int sb = (row * 512 + col * 2) ^ ((row & 7) << 4);
            float t = fast_tanh(p2[rt * 2 + ct][i]);
            float x2o = (float)*(const _Float16*)(AQ + sb);
            float e = x2o - t;
            int li = (rt * 2 + ct) * 4 + i;
            g2h[li >> 3][li & 7] = (_Float16)(e * (1.f - t * t));
            dx2a[rt * 2 + ct][i] = -e;
          }
        }
    }
    // ---- P5: dx2a += g1 @ W1^T (reads AG1 g1); ep: x2 RMW in AQ
    {
#pragma unroll
      for (int ct = 0; ct < 2; ++ct)
        mm_burst<2, 8, 1, 16, 512, 2>(AG1, bpt(Wb1, wave * 2 + ct, lane), lane, &dx2a[ct]);
#pragma unroll
      for (int rt = 0; rt < 2; ++rt)
#pragma unroll
        for (int ct = 0; ct < 2; ++ct) {
          int col = (wave * 2 + ct) * 16 + csub;
#pragma unroll
          for (int i = 0; i < 4; ++i) {
            int row = rt * 16 + rsub + i;
            int sb = (row * 512 + col * 2) ^ ((row & 7) << 4);
            float dx = fminf(1.f, fmaxf(-1.f, dx2a[rt * 2 + ct][i]));
            float x2o = (float)*(const _Float16*)(AQ + sb);
            *(_Float16*)(AQ + sb) = (_Float16)(x2o + ETA * dx);
          }
        }
    }
    __syncthreads();  // B7: all g1 reads done -> AG1 reusable for g2
    // ---- publish g2 into AG1
#pragma unroll
    for (int rt = 0; rt < 2; ++rt)
#pragma unroll
      for (int ct = 0; ct < 2; ++ct) {
        int col = (wave * 2 + ct) * 16 + csub;
#pragma unroll
        for (int i = 0; i < 4; ++i) {
          int row = rt * 16 + rsub + i;
          int sb = (row * 512 + col * 2) ^ ((row & 7) << 4);
          int li = (rt * 2 + ct) * 4 + i;
          *(_Float16*)(AG1 + sb) = g2h[li >> 3][li & 7];
        }
      }
    __syncthreads();  // B8: g2 published
    // ---- P6: dx3 = g2 @ W2^T (reads AG1); B9; ep: x3m += ; x3 image -> AR
    {
      floatx4 acc6[2];
#pragma unroll
      for (int i = 0; i < 2; ++i) acc6[i] = zf;
      mm_burst<2, 8, 1, 8, 512, 1>(AG1, bpt(Wb2, wave, lane), lane, acc6);
      __syncthreads();  // B9: g2 reads done -> AG1 reusable next iter (P1-ep)
      int col = wave * 16 + csub;
#pragma unroll
      for (int rt = 0; rt < 2; ++rt)
#pragma unroll
        for (int i = 0; i < 4; ++i) {
          int row = rt * 16 + rsub + i;
          float dx = fminf(1.f, fmaxf(-1.f, acc6[rt][i]));
          float nv = x3m[rt][i] + ETA * dx;
          x3m[rt][i] = nv;
          int byte = (row * 256 + col * 2) ^ ((row & 7) << 4);
          *(_Float16*)(AR + byte) = (_Float16)nv;
        }
    }
  }

  // write settled x3 (fp32 master)
  {
    int col = wave * 16 + csub;
#pragma unroll
    for (int rt = 0; rt < 2; ++rt)
#pragma unroll
      for (int i = 0; i < 4; ++i) {
        int row = rt * 16 + rsub + i;
        out[(size_t)(row0 + row) * D3 + col] = x3m[rt][i];
      }
  }
}

extern "C" void kernel_launch(void* const* d_in, const int* in_sizes, int n_in,
                              void* d_out, int out_size, void* d_ws, size_t ws_size,
                              hipStream_t stream) {
  const float* x0 = (const float*)d_in[0];
  const float* W0 = (const float*)d_in[1];
  const float* W1 = (const float*)d_in[2];
  const float* W2 = (const float*)d_in[3];
  float* out = (float*)d_out;

  _Float16* pack = (_Float16*)d_ws;
  repack_kernel<<<(PACK_ELEMS + 255) / 256, 256, 0, stream>>>(W0, W1, W2, pack);

  (void)hipFuncSetAttribute(reinterpret_cast<const void*>(settle_kernel),
                            hipFuncAttributeMaxDynamicSharedMemorySize, 98304);
  settle_kernel<<<NBLK, 512, 98304, stream>>>(x0, pack, out);
}

// Round 21
// 990.995 us; speedup vs baseline: 1.2192x; 1.2192x over previous
//
#include <hip/hip_runtime.h>

typedef _Float16 half8 __attribute__((ext_vector_type(8)));
typedef float floatx4 __attribute__((ext_vector_type(4)));

#define DEV_INLINE __device__ __forceinline__

constexpr int D0 = 512, D1 = 256, D2 = 256, D3 = 128;
constexpr int NROWS = 16384;
constexpr int MBLK = 32;            // batch rows per block (spill-free tile)
constexpr int NBLK = NROWS / MBLK;  // 512 blocks (proven-best geometry, r16)
constexpr int KITERS = 16;
constexpr float ETA = 0.1f;

// packed-weight element offsets (fp16 elements) inside d_ws
constexpr int OFF_WF0 = 0;                  // fwd W0: K=256, N=512
constexpr int OFF_WF1 = OFF_WF0 + D1 * D0;  // fwd W1: K=256, N=256
constexpr int OFF_WF2 = OFF_WF1 + D2 * D1;  // fwd W2: K=128, N=256
constexpr int OFF_WB0 = OFF_WF2 + D3 * D2;  // bwd W0^T: K=512, N=256
constexpr int OFF_WB1 = OFF_WB0 + D0 * D1;  // bwd W1^T: K=256, N=256
constexpr int OFF_WB2 = OFF_WB1 + D1 * D2;  // bwd W2^T: K=256, N=128
constexpr int PACK_ELEMS = OFF_WB2 + D2 * D3;  // 458752 elems = 896 KB fp16

// ---------------------------------------------------------------------------
// Repack weights into MFMA B-fragment order + cast x0 to fp16 (if ws fits).
// B-frag layout (16x16x32): lane l supplies B[kt*32 + (l>>4)*8 + j][nt*16 + (l&15)],
// j=0..7 contiguous -> pack index ((kt*NT + nt)*64 + l)*8 + j.
// ---------------------------------------------------------------------------
__global__ void repack_kernel(const float* __restrict__ W0, const float* __restrict__ W1,
                              const float* __restrict__ W2, const float* __restrict__ x0,
                              _Float16* __restrict__ pack, _Float16* __restrict__ x0h,
                              int do_x0) {
  int p = blockIdx.x * 256 + threadIdx.x;
  if (p < PACK_ELEMS) {
    const float* W; int Csrc, Nd, off; bool tr;
    if (p < OFF_WF1)      { W = W0; Csrc = D0; Nd = D0; off = OFF_WF0; tr = false; }
    else if (p < OFF_WF2) { W = W1; Csrc = D1; Nd = D1; off = OFF_WF1; tr = false; }
    else if (p < OFF_WB0) { W = W2; Csrc = D2; Nd = D2; off = OFF_WF2; tr = false; }
    else if (p < OFF_WB1) { W = W0; Csrc = D0; Nd = D1; off = OFF_WB0; tr = true;  }
    else if (p < OFF_WB2) { W = W1; Csrc = D1; Nd = D1; off = OFF_WB1; tr = true;  }
    else                  { W = W2; Csrc = D2; Nd = D3; off = OFF_WB2; tr = true;  }
    int local = p - off;
    int j  = local & 7;
    int l  = (local >> 3) & 63;
    int fr = local >> 9;
    int NT = Nd >> 4;
    int nt = fr % NT, kt = fr / NT;
    int k = kt * 32 + ((l >> 4) << 3) + j;
    int n = nt * 16 + (l & 15);
    float v = tr ? W[n * Csrc + k] : W[k * Csrc + n];
    pack[p] = (_Float16)v;
  } else if (do_x0) {
    int q = p - PACK_ELEMS;
    if (q < NROWS * D0) x0h[q] = (_Float16)x0[q];
  }
}

DEV_INLINE float fast_tanh(float x) {
  float e = __expf(2.f * x);                       // v_exp_f32
  return 1.f - 2.f * __builtin_amdgcn_rcpf(e + 1.f);
}

DEV_INLINE const _Float16* bpt(const _Float16* Bp, int nt, int lane) {
  return Bp + ((size_t)nt * 64 + lane) * 8;
}

// ---------------------------------------------------------------------------
// Register-burst matmul: acc[rt*AS+ct] += A(RT*16 x KSTEPS*32) @ B[nt..nt+CT).
// ALL KSTEPS*CT B-tiles (<=8 = 32 VGPR) issued as one burst of ordinary
// global_load_dwordx4; compiler's per-register vmcnt waits pipeline ~8-deep.
// A in LDS, fp16, row stride STRB bytes, XOR-swizzled by ((row&7)<<4).
// ---------------------------------------------------------------------------
template <int RT, int KSTEPS, int CT, int NTT, int STRB, int AS>
DEV_INLINE void mm_burst(const char* __restrict__ A, const _Float16* __restrict__ bsrc,
                         int lane, floatx4* acc) {
  static_assert(KSTEPS * CT <= 8, "bq register budget");
  const int arow = lane & 15;
  const int aoff = (lane >> 4) << 4;  // byte offset of this lane's 16B k-chunk
  half8 bq[KSTEPS * CT];
#pragma unroll
  for (int s = 0; s < KSTEPS; ++s)
#pragma unroll
    for (int ct = 0; ct < CT; ++ct)
      bq[s * CT + ct] = *(const half8*)(bsrc + (size_t)(s * NTT + ct) * 512);
#pragma unroll
  for (int k0 = 0; k0 < KSTEPS; ++k0) {
    half8 a[RT];
#pragma unroll
    for (int rt = 0; rt < RT; ++rt) {
      int row = rt * 16 + arow;
      int byte = (row * STRB + k0 * 64 + aoff) ^ ((row & 7) << 4);
      a[rt] = *(const half8*)(A + byte);
    }
#pragma unroll
    for (int ct = 0; ct < CT; ++ct)
#pragma unroll
      for (int rt = 0; rt < RT; ++rt)
        acc[rt * AS + ct] =
            __builtin_amdgcn_mfma_f32_16x16x32_f16(a[rt], bq[k0 * CT + ct], acc[rt * AS + ct], 0, 0, 0);
  }
}

// ---------------------------------------------------------------------------
// Persistent settling kernel, MBLK=32 rows, 512 threads (8 waves), 64 KB LDS.
// r16 configuration -- measured optimum of this family (991 us, WRITE 122MB,
// FETCH 1.0GB, 86% L2 hit). Spill-free discipline: no x0 caching (fp16 x0h
// from workspace, L2-resident), bursts <= 8 tiles, worst-phase live ~70 VGPR.
// States fp16 in LDS; x3 fp32 register master; g2 passes through registers.
// LDS (64 KB): AX1[16K]@0: x1[32][256] s512 | AG0[8K]@16K: g0-quarter s256
//   AQ[16K]@24K: x2 s512 | AG1[16K]@40K: g1 s512 then g2 | AR[8K]@56K: x3 s256
// Per iter: P1(+ep g1->AG1), {P3q(ep->AG0), B, P4q, B} x4, P4ep->AX1,
//           P2(ep: dx2a=-e2, g2->regs), P5a, P5ep->AQ, B7, g2->AG1, B8,
//           P6, B9, P6ep->AR. 11 barriers/iter.
// Every C-cell is owned by exactly one thread -> fp16 RMW in LDS race-free.
// ---------------------------------------------------------------------------
__global__ __launch_bounds__(512)
void settle_kernel(const float* __restrict__ x0,
                   const _Float16* __restrict__ x0h,
                   const _Float16* __restrict__ pack,
                   float* __restrict__ out) {
  extern __shared__ char lds[];
  char* AX1 = lds;
  char* AG0 = lds + 16384;
  char* AQ  = lds + 24576;
  char* AG1 = lds + 40960;
  char* AR  = lds + 57344;

  const int tid  = threadIdx.x;
  const int lane = tid & 63;
  const int wave = tid >> 6;
  const int row0 = blockIdx.x * MBLK;
  const int rsub = (lane >> 4) << 2;  // C/D layout: row = (lane>>4)*4 + i
  const int csub = lane & 15;         //             col = lane & 15

  // zero-init x2 (AQ, 16K) and x3 image (AR, 8K)
  {
    floatx4 z = {0.f, 0.f, 0.f, 0.f};
    for (int i = tid; i < 1024; i += 512) ((floatx4*)AQ)[i] = z;
    for (int i = tid; i < 512; i += 512) ((floatx4*)AR)[i] = z;
  }

  const floatx4 zf = {0.f, 0.f, 0.f, 0.f};
  floatx4 x3m[2];  // fp32 master of the output layer [rt]
#pragma unroll
  for (int i = 0; i < 2; ++i) x3m[i] = zf;

  const _Float16* Wf0 = pack + OFF_WF0;
  const _Float16* Wf1 = pack + OFF_WF1;
  const _Float16* Wf2 = pack + OFF_WF2;
  const _Float16* Wb0 = pack + OFF_WB0;
  const _Float16* Wb1 = pack + OFF_WB1;
  const _Float16* Wb2 = pack + OFF_WB2;

  // =================== iteration 0 shortcut ===================
  // all states zero: g0 = x0 (f'(0)=1); only dx1 = x0 @ W0^T is nonzero.
  {
    floatx4 dx1a[4];
#pragma unroll
    for (int i = 0; i < 4; ++i) dx1a[i] = zf;
    for (int q = 0; q < 4; ++q) {
      // stage g0-quarter = x0 cols [q*128, q*128+128) from x0h
      for (int idx = tid; idx < MBLK * 128; idx += 512) {
        int row = idx >> 7, colq = idx & 127;
        size_t gi = (size_t)(row0 + row) * D0 + q * 128 + colq;
        _Float16 v = x0h ? x0h[gi] : (_Float16)x0[gi];
        int byte = (row * 256 + colq * 2) ^ ((row & 7) << 4);
        *(_Float16*)(AG0 + byte) = v;
      }
      __syncthreads();  // publish g0 quarter
      mm_burst<2, 4, 2, 16, 256, 2>(AG0, bpt(Wb0 + q * 32768, wave * 2, lane), lane, dx1a);
      __syncthreads();  // reads done -> AG0 reusable
    }
#pragma unroll
    for (int rt = 0; rt < 2; ++rt)
#pragma unroll
      for (int ct = 0; ct < 2; ++ct) {
        int col = (wave * 2 + ct) * 16 + csub;
#pragma unroll
        for (int i = 0; i < 4; ++i) {
          int row = rt * 16 + rsub + i;
          float dx = fminf(1.f, fmaxf(-1.f, dx1a[rt * 2 + ct][i]));
          int byte = (row * 512 + col * 2) ^ ((row & 7) << 4);
          *(_Float16*)(AX1 + byte) = (_Float16)(ETA * dx);
        }
      }
    __syncthreads();  // publish x1
  }

  // =================== iterations 1..15 ===================
  for (int it = 1; it < KITERS; ++it) {
    floatx4 dx1a[4];
    // ---- P1: preact1 = x2 @ W1 (reads AQ); ep: e1, g1 -> AG1, dx1a = -e1
    {
#pragma unroll
      for (int i = 0; i < 4; ++i) dx1a[i] = zf;
#pragma unroll
      for (int ct = 0; ct < 2; ++ct)
        mm_burst<2, 8, 1, 16, 512, 2>(AQ, bpt(Wf1, wave * 2 + ct, lane), lane, &dx1a[ct]);
#pragma unroll
      for (int rt = 0; rt < 2; ++rt)
#pragma unroll
        for (int ct = 0; ct < 2; ++ct) {
          int col = (wave * 2 + ct) * 16 + csub;
#pragma unroll
          for (int i = 0; i < 4; ++i) {
            int row = rt * 16 + rsub + i;
            int sb = (row * 512 + col * 2) ^ ((row & 7) << 4);
            float t = fast_tanh(dx1a[rt * 2 + ct][i]);
            float x1o = (float)*(const _Float16*)(AX1 + sb);
            float e = x1o - t;
            *(_Float16*)(AG1 + sb) = (_Float16)(e * (1.f - t * t));
            dx1a[rt * 2 + ct][i] = -e;
          }
        }
    }
    // ---- P3/P4 interleaved over the four K/N=128 quarters of g0
    for (int q = 0; q < 4; ++q) {
      // P3q: preact0 cols q*128.. (each wave ONE tile nt = q*8+wave)
      {
        floatx4 acc3[2];
#pragma unroll
        for (int i = 0; i < 2; ++i) acc3[i] = zf;
        mm_burst<2, 8, 1, 32, 512, 1>(AX1, bpt(Wf0, q * 8 + wave, lane), lane, acc3);
        int colq = wave * 16 + csub;
#pragma unroll
        for (int rt = 0; rt < 2; ++rt)
#pragma unroll
          for (int i = 0; i < 4; ++i) {
            int row = rt * 16 + rsub + i;
            float t = fast_tanh(acc3[rt][i]);
            size_t gi = (size_t)(row0 + row) * D0 + q * 128 + colq;
            float xv = x0h ? (float)x0h[gi] : x0[gi];
            float g = (xv - t) * (1.f - t * t);
            int byte = (row * 256 + colq * 2) ^ ((row & 7) << 4);
            *(_Float16*)(AG0 + byte) = (_Float16)g;
          }
      }
      __syncthreads();  // publish g0 quarter
      mm_burst<2, 4, 2, 16, 256, 2>(AG0, bpt(Wb0 + q * 32768, wave * 2, lane), lane, dx1a);
      __syncthreads();  // P4q reads done -> AG0 reusable
    }
    // ---- P4 epilogue: x1 += eta*clip(dx1a)  (RMW own cells of AX1)
#pragma unroll
    for (int rt = 0; rt < 2; ++rt)
#pragma unroll
      for (int ct = 0; ct < 2; ++ct) {
        int col = (wave * 2 + ct) * 16 + csub;
#pragma unroll
        for (int i = 0; i < 4; ++i) {
          int row = rt * 16 + rsub + i;
          int sb = (row * 512 + col * 2) ^ ((row & 7) << 4);
          float dx = fminf(1.f, fmaxf(-1.f, dx1a[rt * 2 + ct][i]));
          float x1o = (float)*(const _Float16*)(AX1 + sb);
          *(_Float16*)(AX1 + sb) = (_Float16)(x1o + ETA * dx);
        }
      }
    // ---- P2: preact2 = x3 @ W2 (reads AR); ep: dx2a = -e2, g2 -> registers
    floatx4 dx2a[4];
    half8 g2h[2];
    {
      floatx4 p2[4];
#pragma unroll
      for (int i = 0; i < 4; ++i) p2[i] = zf;
      mm_burst<2, 4, 2, 16, 256, 2>(AR, bpt(Wf2, wave * 2, lane), lane, p2);
#pragma unroll
      for (int rt = 0; rt < 2; ++rt)
#pragma unroll
        for (int ct = 0; ct < 2; ++ct) {
          int col = (wave * 2 + ct) * 16 + csub;
#pragma unroll
          for (int i = 0; i < 4; ++i) {
            int row = rt * 16 + rsub + i;
            int sb = (row * 512 + col * 2) ^ ((row & 7) << 4);
            float t = fast_tanh(p2[rt * 2 + ct][i]);
            float x2o = (float)*(const _Float16*)(AQ + sb);
            float e = x2o - t;
            int li = (rt * 2 + ct) * 4 + i;
            g2h[li >> 3][li & 7] = (_Float16)(e * (1.f - t * t));
            dx2a[rt * 2 + ct][i] = -e;
          }
        }
    }
    // ---- P5a: dx2a += g1 @ W1^T (reads AG1 g1); P5ep: x2 RMW in AQ
    {
#pragma unroll
      for (int ct = 0; ct < 2; ++ct)
        mm_burst<2, 8, 1, 16, 512, 2>(AG1, bpt(Wb1, wave * 2 + ct, lane), lane, &dx2a[ct]);
#pragma unroll
      for (int rt = 0; rt < 2; ++rt)
#pragma unroll
        for (int ct = 0; ct < 2; ++ct) {
          int col = (wave * 2 + ct) * 16 + csub;
#pragma unroll
          for (int i = 0; i < 4; ++i) {
            int row = rt * 16 + rsub + i;
            int sb = (row * 512 + col * 2) ^ ((row & 7) << 4);
            float dx = fminf(1.f, fmaxf(-1.f, dx2a[rt * 2 + ct][i]));
            float x2o = (float)*(const _Float16*)(AQ + sb);
            *(_Float16*)(AQ + sb) = (_Float16)(x2o + ETA * dx);
          }
        }
    }
    __syncthreads();  // B7: all g1 reads done -> AG1 reusable for g2
    // ---- publish g2 into AG1
#pragma unroll
    for (int rt = 0; rt < 2; ++rt)
#pragma unroll
      for (int ct = 0; ct < 2; ++ct) {
        int col = (wave * 2 + ct) * 16 + csub;
#pragma unroll
        for (int i = 0; i < 4; ++i) {
          int row = rt * 16 + rsub + i;
          int sb = (row * 512 + col * 2) ^ ((row & 7) << 4);
          int li = (rt * 2 + ct) * 4 + i;
          *(_Float16*)(AG1 + sb) = g2h[li >> 3][li & 7];
        }
      }
    __syncthreads();  // B8: g2 published
    // ---- P6: dx3 = g2 @ W2^T (reads AG1); B9; ep: x3m += ; x3 image -> AR
    {
      floatx4 acc6[2];
#pragma unroll
      for (int i = 0; i < 2; ++i) acc6[i] = zf;
      mm_burst<2, 8, 1, 8, 512, 1>(AG1, bpt(Wb2, wave, lane), lane, acc6);
      __syncthreads();  // B9: g2 reads done -> AG1 reusable next iter (P1-ep)
      int col = wave * 16 + csub;
#pragma unroll
      for (int rt = 0; rt < 2; ++rt)
#pragma unroll
        for (int i = 0; i < 4; ++i) {
          int row = rt * 16 + rsub + i;
          float dx = fminf(1.f, fmaxf(-1.f, acc6[rt][i]));
          float nv = x3m[rt][i] + ETA * dx;
          x3m[rt][i] = nv;
          int byte = (row * 256 + col * 2) ^ ((row & 7) << 4);
          *(_Float16*)(AR + byte) = (_Float16)nv;
        }
    }
  }

  // write settled x3 (fp32 master)
  {
    int col = wave * 16 + csub;
#pragma unroll
    for (int rt = 0; rt < 2; ++rt)
#pragma unroll
      for (int i = 0; i < 4; ++i) {
        int row = rt * 16 + rsub + i;
        out[(size_t)(row0 + row) * D3 + col] = x3m[rt][i];
      }
  }
}

extern "C" void kernel_launch(void* const* d_in, const int* in_sizes, int n_in,
                              void* d_out, int out_size, void* d_ws, size_t ws_size,
                              hipStream_t stream) {
  const float* x0 = (const float*)d_in[0];
  const float* W0 = (const float*)d_in[1];
  const float* W1 = (const float*)d_in[2];
  const float* W2 = (const float*)d_in[3];
  float* out = (float*)d_out;

  _Float16* pack = (_Float16*)d_ws;
  const size_t pack_bytes = (size_t)PACK_ELEMS * 2;
  const size_t x0h_bytes = (size_t)NROWS * D0 * 2;
  int do_x0 = (ws_size >= pack_bytes + x0h_bytes) ? 1 : 0;
  _Float16* x0h = do_x0 ? (_Float16*)((char*)d_ws + pack_bytes) : nullptr;

  int total = PACK_ELEMS + (do_x0 ? NROWS * D0 : 0);
  repack_kernel<<<(total + 255) / 256, 256, 0, stream>>>(W0, W1, W2, x0, pack, x0h, do_x0);

  (void)hipFuncSetAttribute(reinterpret_cast<const void*>(settle_kernel),
                            hipFuncAttributeMaxDynamicSharedMemorySize, 65536);
  settle_kernel<<<NBLK, 512, 65536, stream>>>(x0, x0h, pack, out);
}